// Round 1
// baseline (13846.983 us; speedup 1.0000x reference)
//
#include <hip/hip_runtime.h>
#include <hip/hip_fp16.h>

typedef _Float16 half8 __attribute__((ext_vector_type(8)));
typedef float f32x4  __attribute__((ext_vector_type(4)));
typedef float f32x16 __attribute__((ext_vector_type(16)));

#define LSTM_T 512

__device__ __forceinline__ float sigf(float x) {
    return __builtin_amdgcn_rcpf(1.0f + __builtin_amdgcn_exp2f(-1.44269504088896f * x));
}
__device__ __forceinline__ float tanhf_fast(float x) {
    return 2.0f * __builtin_amdgcn_rcpf(1.0f + __builtin_amdgcn_exp2f(-2.88539008177793f * x)) - 1.0f;
}

// Persistent LSTM kernel.
// Grid: 256 WGs x 512 threads. WG(bid): s = bid&3 (batch group, 32 batches),
// jj = bid>>2 (hidden tile, 16 hidden units -> 64 gate rows, interleaved row=4*u+gate).
// 8 waves = (mt in {0,1}) x (kh in {0..3}): M-tile of 32 gate rows, K-quarter of 256.
// W_hh lives in fp16 MFMA A-fragments in VGPRs (64 VGPR/wave). c-state in registers
// of kh==0 waves. One group barrier (64 WGs) per step via counters in d_ws.
__global__ __launch_bounds__(512, 2) void lstm_persist(
    const float* __restrict__ y_hist,  // [128][512]
    const float* __restrict__ W_ih,    // [4096]
    const float* __restrict__ W_hh,    // [4096][1024]
    const float* __restrict__ b_ih,    // [4096]
    const float* __restrict__ b_hh,    // [4096]
    const float* __restrict__ fc_W,    // [128][1024]
    const float* __restrict__ fc_b,    // [128]
    const float* __restrict__ h0,      // [128][1024]
    const float* __restrict__ c0,      // [128][1024]
    float* __restrict__ out,           // [128][128]
    _Float16* __restrict__ hbuf0,      // state ping-pong (fp16) [128][1024]
    _Float16* __restrict__ hbuf1,
    float* __restrict__ hfin,          // fp32 h_T for the FC epilogue
    unsigned int* __restrict__ cnt)    // 4 group counters, 256B apart
{
    __shared__ _Float16 h_lds[32 * 1024];   // 64 KB, rows XOR-swizzled by ((row&7)<<4)
    __shared__ float    y_lds[64][32];      // 8 KB, [t&63][b_loc]
    __shared__ float    red[6 * 1024];      // 24 KB, k-reduction + FC scratch

    const int tid = threadIdx.x;
    const int l   = tid & 63;
    const int wid = tid >> 6;
    const int mt  = wid & 1;
    const int kh  = wid >> 1;
    const int n   = l & 31;     // A-row (gate row) or B-col (batch) within tile
    const int kg  = l >> 5;     // k-group
    const int bid = blockIdx.x;
    const int s   = bid & 3;
    const int jj  = bid >> 2;
    unsigned int* cs = cnt + (s << 6);

    // ---- load W_hh fragments (A operand, fp16) : k = 256*kh + 16*c + 8*kg + j ----
    half8 wfrag[16];
    {
        const int row_loc = 32 * mt + n;                         // 0..63 within WG
        const int grow = (row_loc & 3) * 1024 + 16 * jj + (row_loc >> 2);
        const float* wrow = W_hh + (size_t)grow * 1024 + 256 * kh + 8 * kg;
        #pragma unroll
        for (int c = 0; c < 16; ++c) {
            f32x4 a0 = *(const f32x4*)(wrow + 16 * c);
            f32x4 a1 = *(const f32x4*)(wrow + 16 * c + 4);
            half8 w;
            w[0] = (_Float16)a0[0]; w[1] = (_Float16)a0[1];
            w[2] = (_Float16)a0[2]; w[3] = (_Float16)a0[3];
            w[4] = (_Float16)a1[0]; w[5] = (_Float16)a1[1];
            w[6] = (_Float16)a1[2]; w[7] = (_Float16)a1[3];
            wfrag[c] = w;
        }
    }

    // ---- per-lane epilogue constants (kh==0 waves): lane owns (batch n, u = 8mt+2q+kg) ----
    float wih_r[4][4], bias_r[4][4], creg[4];
    if (kh == 0) {
        #pragma unroll
        for (int q = 0; q < 4; ++q) {
            const int ug = 16 * jj + 8 * mt + 2 * q + kg;
            #pragma unroll
            for (int g = 0; g < 4; ++g) {
                const int gr = g * 1024 + ug;
                wih_r[q][g]  = W_ih[gr];
                bias_r[q][g] = b_ih[gr] + b_hh[gr];
            }
            creg[q] = c0[(size_t)(32 * s + n) * 1024 + ug];
        }
    }

    // B-frag base address (swizzle folded in): see derivation in journal.
    const int q_swz = (n >> 1) & 3;
    const int bbase = n * 2048 + 512 * kh + ((kg ^ (n & 1)) << 4);

    for (int t = 0; t < LSTM_T; ++t) {
        // ---- group barrier: wait until state t is published (64 arrivals per step) ----
        if (t > 0) {
            if (tid == 0) {
                const unsigned tgt = 64u * (unsigned)t;
                while (__hip_atomic_load(cs, __ATOMIC_ACQUIRE,
                                         __HIP_MEMORY_SCOPE_AGENT) < tgt)
                    __builtin_amdgcn_s_sleep(1);
            }
            __syncthreads();
        }
        // ---- stage y tile every 64 steps ----
        if ((t & 63) == 0) {
            const int row = tid >> 4, seg = tid & 15;
            f32x4 yv = *(const f32x4*)(y_hist + (size_t)(32 * s + row) * 512 + t + 4 * seg);
            #pragma unroll
            for (int e = 0; e < 4; ++e) y_lds[4 * seg + e][row] = yv[e];
        }
        // ---- stage h(state t) into LDS (fp16, XOR-swizzled) ----
        {
            const int row = tid >> 4, seg = tid & 15;
            const int swz = (row & 7) << 4;
            char* dst = (char*)(h_lds + row * 1024);
            if (t == 0) {
                const float* src = h0 + (size_t)(32 * s + row) * 1024 + seg * 64;
                #pragma unroll
                for (int u8 = 0; u8 < 8; ++u8) {
                    f32x4 a0 = *(const f32x4*)(src + 8 * u8);
                    f32x4 a1 = *(const f32x4*)(src + 8 * u8 + 4);
                    half8 hv;
                    hv[0]=(_Float16)a0[0]; hv[1]=(_Float16)a0[1];
                    hv[2]=(_Float16)a0[2]; hv[3]=(_Float16)a0[3];
                    hv[4]=(_Float16)a1[0]; hv[5]=(_Float16)a1[1];
                    hv[6]=(_Float16)a1[2]; hv[7]=(_Float16)a1[3];
                    *(half8*)(dst + ((seg * 128 + 16 * u8) ^ swz)) = hv;
                }
            } else {
                const _Float16* src = ((t & 1) ? hbuf1 : hbuf0)
                                      + (size_t)(32 * s + row) * 1024 + seg * 64;
                #pragma unroll
                for (int u8 = 0; u8 < 8; ++u8) {
                    half8 hv = *(const half8*)(src + 8 * u8);
                    *(half8*)(dst + ((seg * 128 + 16 * u8) ^ swz)) = hv;
                }
            }
        }
        __syncthreads();

        // ---- MFMA: gates_tile(32 rows x 32 batches) over this wave's K quarter ----
        f32x16 acc;
        #pragma unroll
        for (int e = 0; e < 16; ++e) acc[e] = 0.0f;
        {
            const char* hb = (const char*)h_lds;
            #pragma unroll
            for (int c = 0; c < 16; ++c) {
                half8 bfrag = *(const half8*)(hb + bbase + ((c ^ q_swz) << 5));
                acc = __builtin_amdgcn_mfma_f32_32x32x16_f16(wfrag[c], bfrag, acc, 0, 0, 0);
            }
        }
        __syncthreads();
        // ---- K reduction: kh 1..3 dump partials, kh==0 accumulates ----
        if (kh != 0) {
            float* rb = red + ((mt * 3 + (kh - 1)) << 10);
            #pragma unroll
            for (int q = 0; q < 4; ++q) {
                f32x4 v = { acc[4*q], acc[4*q+1], acc[4*q+2], acc[4*q+3] };
                *(f32x4*)(rb + q * 256 + l * 4) = v;
            }
        }
        __syncthreads();
        if (kh == 0) {
            const float* rb = red + mt * 3 * 1024;
            #pragma unroll
            for (int r = 0; r < 3; ++r) {
                #pragma unroll
                for (int q = 0; q < 4; ++q) {
                    f32x4 v = *(const f32x4*)(rb + (r << 10) + q * 256 + l * 4);
                    acc[4*q]   += v[0];
                    acc[4*q+1] += v[1];
                    acc[4*q+2] += v[2];
                    acc[4*q+3] += v[3];
                }
            }
            // ---- epilogue: gate nonlinearities, c update, publish h(t+1) ----
            const float yt = y_lds[t & 63][n];
            _Float16* hd = (t & 1) ? hbuf0 : hbuf1;   // buffer of state t+1
            #pragma unroll
            for (int q = 0; q < 4; ++q) {
                float gi = acc[4*q+0] + yt * wih_r[q][0] + bias_r[q][0];
                float gf = acc[4*q+1] + yt * wih_r[q][1] + bias_r[q][1];
                float gg = acc[4*q+2] + yt * wih_r[q][2] + bias_r[q][2];
                float go = acc[4*q+3] + yt * wih_r[q][3] + bias_r[q][3];
                float cnew = sigf(gf) * creg[q] + sigf(gi) * tanhf_fast(gg);
                creg[q] = cnew;
                float hv = sigf(go) * tanhf_fast(cnew);
                const int ug = 16 * jj + 8 * mt + 2 * q + kg;
                const size_t off = (size_t)(32 * s + n) * 1024 + ug;
                hd[off] = (_Float16)hv;
                if (t == LSTM_T - 1) hfin[off] = hv;
            }
            __threadfence();   // release h stores to agent scope
        }
        __syncthreads();
        if (tid == 0)
            __hip_atomic_fetch_add(cs, 1u, __ATOMIC_RELEASE, __HIP_MEMORY_SCOPE_AGENT);
    }

    // ---- final FC: out = h_T @ fc_W^T + fc_b (group-local; h rows of group s only) ----
    if (tid == 0) {
        while (__hip_atomic_load(cs, __ATOMIC_ACQUIRE, __HIP_MEMORY_SCOPE_AGENT)
               < 64u * (unsigned)LSTM_T)
            __builtin_amdgcn_s_sleep(1);
    }
    __syncthreads();
    if (jj < 32) {
        const int b = 32 * s + jj;
        const int o = tid & 127, kq = tid >> 7;
        const float* hf = hfin + (size_t)b * 1024 + kq * 256;
        const float* wr = fc_W + (size_t)o * 1024 + kq * 256;
        float p = 0.0f;
        #pragma unroll 8
        for (int i = 0; i < 256; i += 4) {
            f32x4 a = *(const f32x4*)(hf + i);
            f32x4 w = *(const f32x4*)(wr + i);
            p += a[0]*w[0] + a[1]*w[1] + a[2]*w[2] + a[3]*w[3];
        }
        red[(kq << 7) + o] = p;
        __syncthreads();
        if (tid < 128) {
            out[(size_t)b * 128 + tid] =
                red[tid] + red[128 + tid] + red[256 + tid] + red[384 + tid] + fc_b[tid];
        }
    }
}

extern "C" void kernel_launch(void* const* d_in, const int* in_sizes, int n_in,
                              void* d_out, int out_size, void* d_ws, size_t ws_size,
                              hipStream_t stream) {
    (void)in_sizes; (void)n_in; (void)out_size; (void)ws_size;
    const float* y_hist = (const float*)d_in[0];
    const float* W_ih   = (const float*)d_in[1];
    const float* W_hh   = (const float*)d_in[2];
    const float* b_ih   = (const float*)d_in[3];
    const float* b_hh   = (const float*)d_in[4];
    const float* fc_W   = (const float*)d_in[5];
    const float* fc_b   = (const float*)d_in[6];
    const float* h0     = (const float*)d_in[7];
    const float* c0     = (const float*)d_in[8];

    // d_ws layout: hbuf0 (256K) | hbuf1 (256K) | hfin (512K) | counters (1K). ~1.05 MB.
    char* ws = (char*)d_ws;
    _Float16* hbuf0 = (_Float16*)ws;
    _Float16* hbuf1 = (_Float16*)(ws + (256 << 10));
    float*    hfin  = (float*)(ws + (512 << 10));
    unsigned int* cnt = (unsigned int*)(ws + (1024 << 10));

    hipMemsetAsync(cnt, 0, 1024, stream);   // reset group counters every launch (replay-safe)
    hipLaunchKernelGGL(lstm_persist, dim3(256), dim3(512), 0, stream,
                       y_hist, W_ih, W_hh, b_ih, b_hh, fc_W, fc_b, h0, c0,
                       (float*)d_out, hbuf0, hbuf1, hfin, cnt);
}

// Round 2
// 11559.096 us; speedup vs baseline: 1.1979x; 1.1979x over previous
//
#include <hip/hip_runtime.h>
#include <hip/hip_fp16.h>

typedef _Float16 half8 __attribute__((ext_vector_type(8)));
typedef float f32x4  __attribute__((ext_vector_type(4)));
typedef float f32x16 __attribute__((ext_vector_type(16)));

#define LSTM_T 512

__device__ __forceinline__ float sigf(float x) {
    return __builtin_amdgcn_rcpf(1.0f + __builtin_amdgcn_exp2f(-1.44269504088896f * x));
}
__device__ __forceinline__ float tanhf_fast(float x) {
    return 2.0f * __builtin_amdgcn_rcpf(1.0f + __builtin_amdgcn_exp2f(-2.88539008177793f * x)) - 1.0f;
}

// Persistent LSTM. Grid: 256 WGs x 512 threads, 1 WG/CU (96KB LDS).
// WG(bid): s = bid&3 (batch group, 32 batches), jj = bid>>2 (16 hidden units).
// 8 waves = (mt in {0,1}) x (kh in {0..3}). W_hh in fp16 VGPR fragments.
// Sync: per-WG flags[s*64+jj] = t+1 (release store), readers lane-poll all 64
// flags RELAXED + one threadfence (acquire) per step. No atomic RMW.
// h exchange buffer layout: [group][jj 0..63][brow 0..31][u 0..15] fp16 --
// each WG's step output is 1KB contiguous; stage reads fully lane-coalesced.
__global__ __launch_bounds__(512, 2) void lstm_persist(
    const float* __restrict__ y_hist,  // [128][512]
    const float* __restrict__ W_ih,    // [4096]
    const float* __restrict__ W_hh,    // [4096][1024]
    const float* __restrict__ b_ih,    // [4096]
    const float* __restrict__ b_hh,    // [4096]
    const float* __restrict__ fc_W,    // [128][1024]
    const float* __restrict__ fc_b,    // [128]
    const float* __restrict__ h0,      // [128][1024]
    const float* __restrict__ c0,      // [128][1024]
    float* __restrict__ out,           // [128][128]
    _Float16* __restrict__ hbuf0,      // [4][64][32][16] fp16 (per-group 64KB)
    _Float16* __restrict__ hbuf1,
    float* __restrict__ hfin,          // fp32 h_T [128][1024] for FC
    unsigned int* __restrict__ flags)  // [4][64] u32
{
    __shared__ _Float16 h_lds[32 * 1024];   // 64 KB, [brow][1024u], XOR-swizzled ((brow&7)<<4)
    __shared__ float    y_lds[64][32];      // 8 KB
    __shared__ float    red[6 * 1024];      // 24 KB, k-reduction + FC scratch

    const int tid = threadIdx.x;
    const int l   = tid & 63;
    const int wid = tid >> 6;
    const int mt  = wid & 1;
    const int kh  = wid >> 1;
    const int n   = l & 31;     // A-row (gate row) or B-col (batch) within tile
    const int kg  = l >> 5;     // k-group
    const int bid = blockIdx.x;
    const int s   = bid & 3;
    const int jj  = bid >> 2;
    unsigned int* gflags = flags + (s << 6);

    // ---- load W_hh fragments (A operand, fp16): k = 256*kh + 16*c + 8*kg + j ----
    half8 wfrag[16];
    {
        const int row_loc = 32 * mt + n;
        const int grow = (row_loc & 3) * 1024 + 16 * jj + (row_loc >> 2);
        const float* wrow = W_hh + (size_t)grow * 1024 + 256 * kh + 8 * kg;
        #pragma unroll
        for (int c = 0; c < 16; ++c) {
            f32x4 a0 = *(const f32x4*)(wrow + 16 * c);
            f32x4 a1 = *(const f32x4*)(wrow + 16 * c + 4);
            half8 w;
            w[0] = (_Float16)a0[0]; w[1] = (_Float16)a0[1];
            w[2] = (_Float16)a0[2]; w[3] = (_Float16)a0[3];
            w[4] = (_Float16)a1[0]; w[5] = (_Float16)a1[1];
            w[6] = (_Float16)a1[2]; w[7] = (_Float16)a1[3];
            wfrag[c] = w;
        }
    }

    // ---- per-lane epilogue constants (kh==0 waves): lane owns (batch n, u = 8mt+2q+kg) ----
    float wih_r[4][4], bias_r[4][4], creg[4];
    if (kh == 0) {
        #pragma unroll
        for (int q = 0; q < 4; ++q) {
            const int ug = 16 * jj + 8 * mt + 2 * q + kg;
            #pragma unroll
            for (int g = 0; g < 4; ++g) {
                const int gr = g * 1024 + ug;
                wih_r[q][g]  = W_ih[gr];
                bias_r[q][g] = b_ih[gr] + b_hh[gr];
            }
            creg[q] = c0[(size_t)(32 * s + n) * 1024 + ug];
        }
    }

    // B-frag base address (swizzle folded in)
    const int q_swz = (n >> 1) & 3;
    const int bbase = n * 2048 + 512 * kh + ((kg ^ (n & 1)) << 4);

    for (int t = 0; t < LSTM_T; ++t) {
        // ---- wait for h(t): lane-parallel relaxed poll of 64 flags, then one acquire fence ----
        if (t > 0) {
            if (wid == 0) {
                const unsigned tgt = (unsigned)t;
                for (;;) {
                    unsigned v = __hip_atomic_load(&gflags[l], __ATOMIC_RELAXED,
                                                   __HIP_MEMORY_SCOPE_AGENT);
                    if (__all((int)(v >= tgt))) break;
                    __builtin_amdgcn_s_sleep(2);
                }
                __threadfence();   // acquire: invalidate L1/L2 so stage reads are fresh
            }
            __syncthreads();
        }
        // ---- stage y tile every 64 steps ----
        if ((t & 63) == 0) {
            const int row = tid >> 4, seg = tid & 15;
            f32x4 yv = *(const f32x4*)(y_hist + (size_t)(32 * s + row) * 512 + t + 4 * seg);
            #pragma unroll
            for (int e = 0; e < 4; ++e) y_lds[4 * seg + e][row] = yv[e];
        }
        // ---- stage h(t) into LDS ----
        if (t == 0) {
            const int row = tid >> 4, seg = tid & 15;
            const int swz = (row & 7) << 4;
            char* dst = (char*)(h_lds + row * 1024);
            const float* src = h0 + (size_t)(32 * s + row) * 1024 + seg * 64;
            #pragma unroll
            for (int u8 = 0; u8 < 8; ++u8) {
                f32x4 a0 = *(const f32x4*)(src + 8 * u8);
                f32x4 a1 = *(const f32x4*)(src + 8 * u8 + 4);
                half8 hv;
                hv[0]=(_Float16)a0[0]; hv[1]=(_Float16)a0[1];
                hv[2]=(_Float16)a0[2]; hv[3]=(_Float16)a0[3];
                hv[4]=(_Float16)a1[0]; hv[5]=(_Float16)a1[1];
                hv[6]=(_Float16)a1[2]; hv[7]=(_Float16)a1[3];
                *(half8*)(dst + ((seg * 128 + 16 * u8) ^ swz)) = hv;
            }
        } else {
            // coalesced: F = flat fp16 index in [jj'][brow][u16] layout
            const _Float16* hbg = ((t & 1) ? hbuf1 : hbuf0) + (s << 15);
            #pragma unroll
            for (int i = 0; i < 8; ++i) {
                const int F = (i * 512 + tid) * 8;
                half8 hv = *(const half8*)(hbg + F);
                const int brow = (F >> 4) & 31;
                const int cb = ((F >> 9) << 5) + ((F & 15) << 1);   // within-row byte col
                *(half8*)((char*)h_lds + brow * 2048 + (cb ^ ((brow & 7) << 4))) = hv;
            }
        }
        __syncthreads();

        // ---- MFMA: gates_tile(32 rows x 32 batches) over this wave's K quarter ----
        f32x16 acc;
        #pragma unroll
        for (int e = 0; e < 16; ++e) acc[e] = 0.0f;
        {
            const char* hb = (const char*)h_lds;
            #pragma unroll
            for (int c = 0; c < 16; ++c) {
                half8 bfrag = *(const half8*)(hb + bbase + ((c ^ q_swz) << 5));
                acc = __builtin_amdgcn_mfma_f32_32x32x16_f16(wfrag[c], bfrag, acc, 0, 0, 0);
            }
        }
        __syncthreads();
        // ---- K reduction: kh 1..3 dump partials, kh==0 accumulates ----
        if (kh != 0) {
            float* rb = red + ((mt * 3 + (kh - 1)) << 10);
            #pragma unroll
            for (int q = 0; q < 4; ++q) {
                f32x4 v = { acc[4*q], acc[4*q+1], acc[4*q+2], acc[4*q+3] };
                *(f32x4*)(rb + q * 256 + l * 4) = v;
            }
        }
        __syncthreads();
        if (kh == 0) {
            const float* rb = red + mt * 3 * 1024;
            #pragma unroll
            for (int r = 0; r < 3; ++r) {
                #pragma unroll
                for (int q = 0; q < 4; ++q) {
                    f32x4 v = *(const f32x4*)(rb + (r << 10) + q * 256 + l * 4);
                    acc[4*q]   += v[0];
                    acc[4*q+1] += v[1];
                    acc[4*q+2] += v[2];
                    acc[4*q+3] += v[3];
                }
            }
            // ---- epilogue: gates, c update, publish h(t+1) (1KB contiguous per WG) ----
            const float yt = y_lds[t & 63][n];
            _Float16* hdg = ((t & 1) ? hbuf0 : hbuf1) + (s << 15) + jj * 512;
            #pragma unroll
            for (int q = 0; q < 4; ++q) {
                float gi = acc[4*q+0] + yt * wih_r[q][0] + bias_r[q][0];
                float gf = acc[4*q+1] + yt * wih_r[q][1] + bias_r[q][1];
                float gg = acc[4*q+2] + yt * wih_r[q][2] + bias_r[q][2];
                float go = acc[4*q+3] + yt * wih_r[q][3] + bias_r[q][3];
                float cnew = sigf(gf) * creg[q] + sigf(gi) * tanhf_fast(gg);
                creg[q] = cnew;
                float hv = sigf(go) * tanhf_fast(cnew);
                const int u_loc = 8 * mt + 2 * q + kg;
                hdg[n * 16 + u_loc] = (_Float16)hv;
                if (t == LSTM_T - 1)
                    hfin[(size_t)(32 * s + n) * 1024 + 16 * jj + u_loc] = hv;
            }
            __threadfence();   // release: drain h stores to agent-visible point
        }
        __syncthreads();
        if (tid == 0)
            __hip_atomic_store(&gflags[jj], (unsigned)(t + 1), __ATOMIC_RELEASE,
                               __HIP_MEMORY_SCOPE_AGENT);
    }

    // ---- final FC: out = h_T @ fc_W^T + fc_b (WG jj<32 handles batch 32s+jj) ----
    if (jj < 32) {
        if (wid == 0) {
            for (;;) {
                unsigned v = __hip_atomic_load(&gflags[l], __ATOMIC_RELAXED,
                                               __HIP_MEMORY_SCOPE_AGENT);
                if (__all((int)(v >= (unsigned)LSTM_T))) break;
                __builtin_amdgcn_s_sleep(2);
            }
            __threadfence();
        }
        __syncthreads();
        const int b = 32 * s + jj;
        const int o = tid & 127, kq = tid >> 7;
        const float* hf = hfin + (size_t)b * 1024 + kq * 256;
        const float* wr = fc_W + (size_t)o * 1024 + kq * 256;
        float p = 0.0f;
        #pragma unroll 8
        for (int i = 0; i < 256; i += 4) {
            f32x4 a = *(const f32x4*)(hf + i);
            f32x4 w = *(const f32x4*)(wr + i);
            p += a[0]*w[0] + a[1]*w[1] + a[2]*w[2] + a[3]*w[3];
        }
        red[(kq << 7) + o] = p;
        __syncthreads();
        if (tid < 128) {
            out[(size_t)b * 128 + tid] =
                red[tid] + red[128 + tid] + red[256 + tid] + red[384 + tid] + fc_b[tid];
        }
    }
}

extern "C" void kernel_launch(void* const* d_in, const int* in_sizes, int n_in,
                              void* d_out, int out_size, void* d_ws, size_t ws_size,
                              hipStream_t stream) {
    (void)in_sizes; (void)n_in; (void)out_size; (void)ws_size;
    const float* y_hist = (const float*)d_in[0];
    const float* W_ih   = (const float*)d_in[1];
    const float* W_hh   = (const float*)d_in[2];
    const float* b_ih   = (const float*)d_in[3];
    const float* b_hh   = (const float*)d_in[4];
    const float* fc_W   = (const float*)d_in[5];
    const float* fc_b   = (const float*)d_in[6];
    const float* h0     = (const float*)d_in[7];
    const float* c0     = (const float*)d_in[8];

    // d_ws layout: hbuf0 (256K) | hbuf1 (256K) | hfin (512K) | flags (1K). ~1.05 MB.
    char* ws = (char*)d_ws;
    _Float16* hbuf0 = (_Float16*)ws;
    _Float16* hbuf1 = (_Float16*)(ws + (256 << 10));
    float*    hfin  = (float*)(ws + (512 << 10));
    unsigned int* flags = (unsigned int*)(ws + (1024 << 10));

    hipMemsetAsync(flags, 0, 1024, stream);   // reset flags every launch (replay-safe)
    hipLaunchKernelGGL(lstm_persist, dim3(256), dim3(512), 0, stream,
                       y_hist, W_ih, W_hh, b_ih, b_hh, fc_W, fc_b, h0, c0,
                       (float*)d_out, hbuf0, hbuf1, hfin, flags);
}

// Round 3
// 2279.624 us; speedup vs baseline: 6.0742x; 5.0706x over previous
//
#include <hip/hip_runtime.h>
#include <hip/hip_fp16.h>

typedef _Float16 half8 __attribute__((ext_vector_type(8)));
typedef float f32x4 __attribute__((ext_vector_type(4)));

#define T_STEPS 512

__device__ __forceinline__ float sigf(float x) {
    return __builtin_amdgcn_rcpf(1.0f + __builtin_amdgcn_exp2f(-1.44269504088896f * x));
}
__device__ __forceinline__ float tanhf_fast(float x) {
    return 2.0f * __builtin_amdgcn_rcpf(1.0f + __builtin_amdgcn_exp2f(-2.88539008177793f * x)) - 1.0f;
}

// Persistent LSTM, fence-free sync design.
// 8 groups x 16 batches; 32 WGs/group; WG = 32 hidden units (128 gate rows,
// interleaved row = 4*u + gate). 8 waves/WG, wave mt owns M-tile rows
// 16mt..16mt+15, FULL K=1024 (32 x mfma_f32_16x16x32_f16, W_hh in 128 VGPRs).
// C/D: col=lane&15 (batch), row=4*(lane>>4)+reg -> each lane holds all 4 gates
// of one (batch,unit): epilogue + c-state per-lane, no k-reduction.
// ALL cross-WG traffic via RELAXED agent-scope atomics (bypass L1/L2 to MALL):
// no threadfence, no buffer_wbl2/buffer_inv. Ordering: h stores -> asm
// s_waitcnt vmcnt(0) -> relaxed flag store; readers poll relaxed then load.
__global__ __launch_bounds__(512, 2) void lstm_persist(
    const float* __restrict__ y_hist,  // [128][512]
    const float* __restrict__ W_ih,    // [4096]
    const float* __restrict__ W_hh,    // [4096][1024]
    const float* __restrict__ b_ih,    // [4096]
    const float* __restrict__ b_hh,    // [4096]
    const float* __restrict__ fc_W,    // [128][1024]
    const float* __restrict__ fc_b,    // [128]
    const float* __restrict__ h0,      // [128][1024]
    const float* __restrict__ c0,      // [128][1024]
    float* __restrict__ out,           // [128][128]
    unsigned long long* __restrict__ hbuf0,  // [8][4096] u64 = [grp][jjp][n][u] fp16
    unsigned long long* __restrict__ hbuf1,
    unsigned int* __restrict__ flags)        // [8][32]
{
    __shared__ _Float16 h_lds[16 * 1024];        // 32KB [n][k], byte^((n&7)<<4)
    __shared__ float    y_lds[512][16];          // 32KB, whole y tile, loaded once
    __shared__ unsigned long long hout_lds[128]; // 1KB h(t+1) transpose buffer
    __shared__ char pad_lds[24576];              // force 1 WG/CU (89KB total)

    const int tid = threadIdx.x;
    const int l   = tid & 63;
    const int wid = tid >> 6;          // mt: M-tile 0..7
    const int q4  = l >> 4;            // k-group / C-row quadrant
    const int n   = l & 15;            // batch within group (B cols / C cols)
    const int bid = blockIdx.x;
    const int s   = bid & 7;           // group (XCD-friendly spread)
    const int jj  = bid >> 3;          // 0..31: units 32jj..32jj+31
    if ((unsigned long long)y_hist == 1ull) pad_lds[tid] = 1;  // keep pad alive

    // ---- W_hh -> fp16 A-fragments in VGPRs (full K), 128 VGPR/lane ----
    // A: row = lane&15 (row_loc = 16*wid + r16), k = 32c + 8*q4 + j
    half8 wfrag[32];
    {
        const int r16  = l & 15;
        const int u_a  = 4 * wid + (r16 >> 2);
        const int g_a  = r16 & 3;
        const int grow = g_a * 1024 + 32 * jj + u_a;
        const float* wrow = W_hh + (size_t)grow * 1024 + 8 * q4;
        #pragma unroll
        for (int c = 0; c < 32; ++c) {
            f32x4 a0 = *(const f32x4*)(wrow + 32 * c);
            f32x4 a1 = *(const f32x4*)(wrow + 32 * c + 4);
            half8 w;
            w[0]=(_Float16)a0[0]; w[1]=(_Float16)a0[1];
            w[2]=(_Float16)a0[2]; w[3]=(_Float16)a0[3];
            w[4]=(_Float16)a1[0]; w[5]=(_Float16)a1[1];
            w[6]=(_Float16)a1[2]; w[7]=(_Float16)a1[3];
            wfrag[c] = w;
        }
    }

    // ---- per-lane epilogue constants: lane owns (batch n, unit u_e = 4*wid+q4) ----
    const int u_e = 4 * wid + q4;
    float wih_r[4], bias_r[4], creg;
    #pragma unroll
    for (int g = 0; g < 4; ++g) {
        const int gr = g * 1024 + 32 * jj + u_e;
        wih_r[g]  = W_ih[gr];
        bias_r[g] = b_ih[gr] + b_hh[gr];
    }
    creg = c0[(size_t)(16 * s + n) * 1024 + 32 * jj + u_e];

    // ---- preload whole y tile for this group's 16 batches (once) ----
    {
        const int r = tid >> 5, sg = tid & 31;
        const float* yr = y_hist + (size_t)(16 * s + r) * 512;
        #pragma unroll
        for (int e = 0; e < 4; ++e) {
            f32x4 v = *(const f32x4*)(yr + sg * 4 + 128 * e);
            #pragma unroll
            for (int j = 0; j < 4; ++j) y_lds[sg * 4 + 128 * e + j][r] = v[j];
        }
    }
    // ---- stage h(0) = h0 (fp32, immutable input: plain cached loads OK) ----
    {
        const int r = tid >> 5, sg = tid & 31;
        const int swz = (r & 7) << 4;
        const float* hr = h0 + (size_t)(16 * s + r) * 1024 + sg * 32;
        char* db = (char*)h_lds + r * 2048;
        #pragma unroll
        for (int v = 0; v < 4; ++v) {
            f32x4 a0 = *(const f32x4*)(hr + 8 * v);
            f32x4 a1 = *(const f32x4*)(hr + 8 * v + 4);
            half8 hv;
            hv[0]=(_Float16)a0[0]; hv[1]=(_Float16)a0[1];
            hv[2]=(_Float16)a0[2]; hv[3]=(_Float16)a0[3];
            hv[4]=(_Float16)a1[0]; hv[5]=(_Float16)a1[1];
            hv[6]=(_Float16)a1[2]; hv[7]=(_Float16)a1[3];
            *(half8*)(db + ((sg * 64 + 16 * v) ^ swz)) = hv;
        }
    }
    __syncthreads();

    const int bb  = n * 2048 + 16 * q4;   // B-frag base byte (pre-swizzle)
    const int swz = (n & 7) << 4;

    for (int t = 0; t < T_STEPS; ++t) {
        if (t > 0) {
            // ---- wait for h(t): relaxed lane-parallel poll (no cache ops) ----
            if (wid == 0) {
                for (;;) {
                    unsigned v = __hip_atomic_load(&flags[(s << 5) + (l & 31)],
                                                   __ATOMIC_RELAXED,
                                                   __HIP_MEMORY_SCOPE_AGENT);
                    if (__all((int)(v >= (unsigned)t))) break;
                    __builtin_amdgcn_s_sleep(1);
                }
            }
            __syncthreads();
            // ---- stage h(t): 32KB via relaxed u64 loads (from MALL), swizzled LDS ----
            const unsigned long long* gb = ((t & 1) ? hbuf1 : hbuf0) + (s << 12);
            #pragma unroll
            for (int i = 0; i < 8; ++i) {
                const int F = i * 512 + tid;
                unsigned long long v = __hip_atomic_load(gb + F, __ATOMIC_RELAXED,
                                                         __HIP_MEMORY_SCOPE_AGENT);
                const int n2 = (F >> 3) & 15;
                const int off = (n2 * 2048 + ((F >> 7) * 64 + (F & 7) * 8))
                                ^ ((n2 & 7) << 4);
                *(unsigned long long*)((char*)h_lds + off) = v;
            }
            __syncthreads();
        }

        // ---- MFMA: 16 rows x 16 batches, full K=1024, 2 independent chains ----
        f32x4 acc0 = {0.f, 0.f, 0.f, 0.f}, acc1 = {0.f, 0.f, 0.f, 0.f};
        {
            const char* hb = (const char*)h_lds;
            #pragma unroll
            for (int c = 0; c < 16; ++c) {
                half8 b0 = *(const half8*)(hb + ((bb + 64 * c) ^ swz));
                half8 b1 = *(const half8*)(hb + ((bb + 64 * c + 1024) ^ swz));
                acc0 = __builtin_amdgcn_mfma_f32_16x16x32_f16(wfrag[c], b0, acc0, 0, 0, 0);
                acc1 = __builtin_amdgcn_mfma_f32_16x16x32_f16(wfrag[c + 16], b1, acc1, 0, 0, 0);
            }
        }
        // ---- epilogue: all 4 gates of (batch n, unit u_e) in-register ----
        {
            const float yt = y_lds[t][n];
            float gi = acc0[0] + acc1[0] + yt * wih_r[0] + bias_r[0];
            float gf = acc0[1] + acc1[1] + yt * wih_r[1] + bias_r[1];
            float gg = acc0[2] + acc1[2] + yt * wih_r[2] + bias_r[2];
            float go = acc0[3] + acc1[3] + yt * wih_r[3] + bias_r[3];
            float cn = sigf(gf) * creg + sigf(gi) * tanhf_fast(gg);
            creg = cn;
            float hv = sigf(go) * tanhf_fast(cn);
            ((_Float16*)hout_lds)[n * 32 + u_e] = (_Float16)hv;
        }
        __syncthreads();
        // ---- publish h(t+1): 1KB contiguous, 2 coalesced relaxed u64 stores ----
        if (wid == 0) {
            unsigned long long* ob = ((t & 1) ? hbuf0 : hbuf1) + (s << 12) + (jj << 7);
            unsigned long long v0 = hout_lds[l];
            unsigned long long v1 = hout_lds[l + 64];
            __hip_atomic_store(ob + l, v0, __ATOMIC_RELAXED, __HIP_MEMORY_SCOPE_AGENT);
            __hip_atomic_store(ob + l + 64, v1, __ATOMIC_RELAXED, __HIP_MEMORY_SCOPE_AGENT);
            asm volatile("s_waitcnt vmcnt(0)" ::: "memory");   // stores ACKed at MALL
            if (l == 0)
                __hip_atomic_store(&flags[(s << 5) + jj], (unsigned)(t + 1),
                                   __ATOMIC_RELAXED, __HIP_MEMORY_SCOPE_AGENT);
        }
    }

    // ---- final FC: WG (s, jj<16) -> batch b = 16s+jj; h_T is in hbuf0 (fp16) ----
    if (jj < 16) {
        if (wid == 0) {
            for (;;) {
                unsigned v = __hip_atomic_load(&flags[(s << 5) + (l & 31)],
                                               __ATOMIC_RELAXED,
                                               __HIP_MEMORY_SCOPE_AGENT);
                if (__all((int)(v >= (unsigned)T_STEPS))) break;
                __builtin_amdgcn_s_sleep(1);
            }
        }
        __syncthreads();
        float* hT  = (float*)h_lds;       // 4KB
        float* red = hT + 1024;           // 2KB
        if (tid < 256) {
            const int jjp = tid >> 3, u8 = tid & 7;
            unsigned long long v = __hip_atomic_load(
                hbuf0 + (s << 12) + jjp * 128 + jj * 8 + u8,
                __ATOMIC_RELAXED, __HIP_MEMORY_SCOPE_AGENT);
            const _Float16* hp = (const _Float16*)&v;
            #pragma unroll
            for (int e = 0; e < 4; ++e) hT[32 * jjp + 4 * u8 + e] = (float)hp[e];
        }
        __syncthreads();
        {
            const int o = tid & 127, kq = tid >> 7;
            const float* wr = fc_W + (size_t)o * 1024 + kq * 256;
            const float* hp = hT + kq * 256;
            float p = 0.0f;
            #pragma unroll 8
            for (int i = 0; i < 256; i += 4) {
                f32x4 a = *(const f32x4*)(hp + i);
                f32x4 w = *(const f32x4*)(wr + i);
                p += a[0]*w[0] + a[1]*w[1] + a[2]*w[2] + a[3]*w[3];
            }
            red[kq * 128 + o] = p;
        }
        __syncthreads();
        if (tid < 128) {
            out[(size_t)(16 * s + jj) * 128 + tid] =
                red[tid] + red[128 + tid] + red[256 + tid] + red[384 + tid] + fc_b[tid];
        }
    }
}

extern "C" void kernel_launch(void* const* d_in, const int* in_sizes, int n_in,
                              void* d_out, int out_size, void* d_ws, size_t ws_size,
                              hipStream_t stream) {
    (void)in_sizes; (void)n_in; (void)out_size; (void)ws_size;
    const float* y_hist = (const float*)d_in[0];
    const float* W_ih   = (const float*)d_in[1];
    const float* W_hh   = (const float*)d_in[2];
    const float* b_ih   = (const float*)d_in[3];
    const float* b_hh   = (const float*)d_in[4];
    const float* fc_W   = (const float*)d_in[5];
    const float* fc_b   = (const float*)d_in[6];
    const float* h0     = (const float*)d_in[7];
    const float* c0     = (const float*)d_in[8];

    // d_ws: hbuf0 (256KB) | hbuf1 (256KB) | flags (1KB)
    char* ws = (char*)d_ws;
    unsigned long long* hbuf0 = (unsigned long long*)ws;
    unsigned long long* hbuf1 = (unsigned long long*)(ws + (256 << 10));
    unsigned int*       flags = (unsigned int*)(ws + (512 << 10));

    hipMemsetAsync(flags, 0, 1024, stream);   // replay-safe flag reset
    hipLaunchKernelGGL(lstm_persist, dim3(256), dim3(512), 0, stream,
                       y_hist, W_ih, W_hh, b_ih, b_hh, fc_W, fc_b, h0, c0,
                       (float*)d_out, hbuf0, hbuf1, flags);
}